// Round 6
// baseline (369.083 us; speedup 1.0000x reference)
//
#include <hip/hip_runtime.h>

// Problem geometry (from reference):
//   COMPRESSED_SHAPE = (8192, 64, 128) int4 values -> N_UNPACKED = 67,108,864
//   N_PACKED = 33,554,432 packed bytes, each stored as ONE int32 in [0,256)
//   scale/zero_point: (8192*64) fp32, one per group of 128 unpacked values
//   output dtype contract: reference returns float16, which is NOT bfloat16,
//   so per the harness contract d_out is FLOAT32 (67,108,864 floats, 256 MiB).
//   (Rounds 0-2 all showed absmax == max|ref| == 0.414 because only the first
//    128 MiB was ever written — 16-bit outputs were the bug, not the math.
//    Rounds 3-5 were infra failures; this resubmits the round-2-theory kernel.)
#define N_PACKED_BYTES (8192 * 64 * 64)      // 33,554,432
#define NQ (N_PACKED_BYTES / 4)              // 8,388,608 int4-quads (8 outputs each)

__global__ __launch_bounds__(256) void dequant_int4_kernel(
    const int4* __restrict__ w,        // packed bytes, one per int32, read 4 at a time
    const float* __restrict__ scale,   // (8192*64)
    const float* __restrict__ zp,      // (8192*64)
    float4* __restrict__ out)          // 2x float4 per quad
{
    const int stride = gridDim.x * blockDim.x;
    for (int q = blockIdx.x * blockDim.x + threadIdx.x; q < NQ; q += stride) {
        const int4 wv = w[q];
        // quad q covers unpacked flat [8q, 8q+8) -> group = 8q/128 = q/16
        const int g = q >> 4;
        const float s = scale[g];
        const float z = zp[g];

        const int b0 = wv.x, b1 = wv.y, b2 = wv.z, b3 = wv.w;
        float4 lo, hi;
        lo.x = fmaf((float)(b0 & 0xF), s, z);
        lo.y = fmaf((float)((b0 >> 4) & 0xF), s, z);
        lo.z = fmaf((float)(b1 & 0xF), s, z);
        lo.w = fmaf((float)((b1 >> 4) & 0xF), s, z);
        hi.x = fmaf((float)(b2 & 0xF), s, z);
        hi.y = fmaf((float)((b2 >> 4) & 0xF), s, z);
        hi.z = fmaf((float)(b3 & 0xF), s, z);
        hi.w = fmaf((float)((b3 >> 4) & 0xF), s, z);

        out[2 * q]     = lo;
        out[2 * q + 1] = hi;
    }
}

extern "C" void kernel_launch(void* const* d_in, const int* in_sizes, int n_in,
                              void* d_out, int out_size, void* d_ws, size_t ws_size,
                              hipStream_t stream) {
    const int4*  w     = (const int4*)d_in[0];   // int32 weight, 4 at a time
    const float* scale = (const float*)d_in[1];
    const float* zp    = (const float*)d_in[2];
    float4* out = (float4*)d_out;

    // 2048 blocks x 256 threads = 524,288 threads; NQ / 524,288 = 16 exact iters.
    const int blocks = 2048;
    dequant_int4_kernel<<<blocks, 256, 0, stream>>>(w, scale, zp, out);
}

// Round 11
// 358.839 us; speedup vs baseline: 1.0285x; 1.0285x over previous
//
#include <hip/hip_runtime.h>

// Problem geometry (from reference):
//   COMPRESSED_SHAPE = (8192, 64, 128) int4 values -> N_UNPACKED = 67,108,864
//   N_PACKED = 33,554,432 packed bytes, each stored as ONE int32 in [0,256)
//   scale/zero_point: (8192*64) fp32, one per group of 128 unpacked values
//   d_out: FLOAT32 (reference output fp16 -> "else float*"), 67,108,864 floats.
//   Round 6 PASSED (absmax 1.95e-3, dur_us 369; kernel <=164us, ranked below
//   the 1 GiB poison fills). This round: dense-store restructure — one int2
//   load (2 packed bytes = 4 outputs) -> one dense float4 store per thread.
//   Round 9 failed COMPILE: __builtin_nontemporal_* rejects HIP_vector_type;
//   fixed via clang ext_vector_type. Round 10 was an infra failure; resubmit.
#define N_PACKED_BYTES (8192 * 64 * 64)      // 33,554,432
#define NPAIR (N_PACKED_BYTES / 2)           // 16,777,216 int32-pairs -> one float4 each

typedef int   vi2 __attribute__((ext_vector_type(2)));
typedef float vf4 __attribute__((ext_vector_type(4)));

__global__ __launch_bounds__(256) void dequant_int4_kernel(
    const vi2* __restrict__ w,         // 2 packed bytes (as 2 int32) per thread-iter
    const float* __restrict__ scale,   // (8192*64)
    const float* __restrict__ zp,      // (8192*64)
    vf4* __restrict__ out)             // 1 dense float4 per thread-iter
{
    const int stride = gridDim.x * blockDim.x;
    for (int p = blockIdx.x * blockDim.x + threadIdx.x; p < NPAIR; p += stride) {
        const vi2 wv = __builtin_nontemporal_load(&w[p]);
        // pair p covers unpacked flat [4p, 4p+4) -> group = 4p/128 = p/32
        // (32 consecutive lanes share g -> 2 distinct scale/zp loads per wave)
        const int g = p >> 5;
        const float s = scale[g];
        const float z = zp[g];

        vf4 o;
        o.x = fmaf((float)(wv.x & 0xF), s, z);
        o.y = fmaf((float)((wv.x >> 4) & 0xF), s, z);
        o.z = fmaf((float)(wv.y & 0xF), s, z);
        o.w = fmaf((float)((wv.y >> 4) & 0xF), s, z);

        __builtin_nontemporal_store(o, &out[p]);
    }
}

extern "C" void kernel_launch(void* const* d_in, const int* in_sizes, int n_in,
                              void* d_out, int out_size, void* d_ws, size_t ws_size,
                              hipStream_t stream) {
    const vi2*   w     = (const vi2*)d_in[0];
    const float* scale = (const float*)d_in[1];
    const float* zp    = (const float*)d_in[2];
    vf4* out = (vf4*)d_out;

    // 2048 blocks x 256 threads = 524,288 threads; NPAIR / 524,288 = 32 exact iters.
    const int blocks = 2048;
    dequant_int4_kernel<<<blocks, 256, 0, stream>>>(w, scale, zp, out);
}